// Round 8
// baseline (309.067 us; speedup 1.0000x reference)
//
#include <hip/hip_runtime.h>
#include <stdint.h>
#include <math.h>

#define B_ 16
#define N_ 16
#define H_ 640
#define W_ 640
#define PH_ 300
#define PW_ 300

#define IMG_ELEMS (H_*W_*3)        // 1228800
#define PATCH_ELEMS (PH_*PW_*3)    // 270000

// tiles: 16 rows x 64 cols; 40 x 10 = 400 tiles/image; 6400 total
#define TROWS 16
#define TCOLS 64
#define TILES_Y (H_/TROWS)
#define TILES_X (W_/TCOLS)
#define TILES_PER_IMG (TILES_Y*TILES_X)
#define NTILES (B_*TILES_PER_IMG)

typedef float f32x4 __attribute__((ext_vector_type(4)));

// ---------------- JAX Threefry-2x32-20, bit-exact ----------------
__device__ __forceinline__ uint2 tf2x32(uint32_t k0, uint32_t k1, uint32_t x0, uint32_t x1) {
  uint32_t k2 = k0 ^ k1 ^ 0x1BD11BDAu;
#define TFR(r) x0 += x1; x1 = (x1 << (r)) | (x1 >> (32 - (r))); x1 ^= x0;
  x0 += k0; x1 += k1;
  TFR(13) TFR(15) TFR(26) TFR(6)
  x0 += k1; x1 += k2 + 1u;
  TFR(17) TFR(29) TFR(16) TFR(24)
  x0 += k2; x1 += k0 + 2u;
  TFR(13) TFR(15) TFR(26) TFR(6)
  x0 += k0; x1 += k1 + 3u;
  TFR(17) TFR(29) TFR(16) TFR(24)
  x0 += k1; x1 += k2 + 4u;
  TFR(13) TFR(15) TFR(26) TFR(6)
  x0 += k2; x1 += k0 + 5u;
#undef TFR
  return make_uint2(x0, x1);
}

__device__ __forceinline__ uint32_t rb32(uint32_t k0, uint32_t k1, uint32_t i) {
  uint2 o = tf2x32(k0, k1, 0u, i);
  return o.x ^ o.y;
}

__device__ __forceinline__ float u01f(uint32_t bits) {
  return __uint_as_float((bits >> 9) | 0x3F800000u) - 1.0f;
}

// XLA f32 ErfInv (Giles polynomial) — matches lax.erf_inv
__device__ __forceinline__ float erfinv32(float x) {
  float w = -log1pf(-x * x);
  float p;
  if (w < 5.0f) {
    w = w - 2.5f;
    p = 2.81022636e-08f;
    p = fmaf(p, w, 3.43273939e-07f);
    p = fmaf(p, w, -3.5233877e-06f);
    p = fmaf(p, w, -4.39150654e-06f);
    p = fmaf(p, w, 0.00021858087f);
    p = fmaf(p, w, -0.00125372503f);
    p = fmaf(p, w, -0.00417768164f);
    p = fmaf(p, w, 0.246640727f);
    p = fmaf(p, w, 1.50140941f);
  } else {
    w = sqrtf(w) - 3.0f;
    p = -0.000200214257f;
    p = fmaf(p, w, 0.000100950558f);
    p = fmaf(p, w, 0.00134934322f);
    p = fmaf(p, w, -0.00367342844f);
    p = fmaf(p, w, 0.00573950773f);
    p = fmaf(p, w, -0.0076224613f);
    p = fmaf(p, w, 0.00943887047f);
    p = fmaf(p, w, 1.00167406f);
    p = fmaf(p, w, 2.83297682f);
  }
  return p * x;
}

__device__ __forceinline__ float jnormal(uint32_t bits) {
  float lo = __uint_as_float(0xBF7FFFFFu);  // nextafterf(-1,0)
  float span = 1.0f - lo;                   // rounds to 2.0f, same as XLA
  float u = fmaxf(lo, u01f(bits) * span + lo);
  return 1.4142135623730951f * erfinv32(u);
}

// ---------------- per-(image,box) parameters ----------------
// params[t*16]: 0 y0i, 1 x0i, 2 diagi, 3 phi, 4 c, 5 ca, 6 sa, 7 top,
//               8 bright, 9 300/phi, 10 unused, 11 valid, 12 k2a, 13 k2b
__global__ void setup_kernel(const float* __restrict__ boxes, const float* __restrict__ scale_p,
                             float* __restrict__ params, float* __restrict__ wb) {
  int t = threadIdx.x;
  if (t >= B_*N_) return;
  int b = t >> 4, n = t & 15;
  uint2 kb = tf2x32(0u, 42u, 0u, (uint32_t)b);
  uint2 kw  = tf2x32(kb.x, kb.y, 0u, 0u);
  uint2 kbk = tf2x32(kb.x, kb.y, 0u, 1u);
  uint2 kl  = tf2x32(kb.x, kb.y, 0u, 2u);
  if (n == 0) {
    wb[b*8+0] = jnormal(rb32(kw.x,  kw.y,  0u)) * 0.1f + 0.5f;
    wb[b*8+1] = jnormal(rb32(kw.x,  kw.y,  1u)) * 0.1f + 0.5f;
    wb[b*8+2] = jnormal(rb32(kw.x,  kw.y,  2u)) * 0.1f + 0.5f;
    wb[b*8+3] = jnormal(rb32(kbk.x, kbk.y, 0u)) * 0.01f;
    wb[b*8+4] = jnormal(rb32(kbk.x, kbk.y, 1u)) * 0.01f;
    wb[b*8+5] = jnormal(rb32(kbk.x, kbk.y, 2u)) * 0.01f;
  }
  uint2 kk = tf2x32(kl.x, kl.y, 0u, (uint32_t)n);
  uint2 k1 = tf2x32(kk.x, kk.y, 0u, 0u);
  uint2 k2 = tf2x32(kk.x, kk.y, 0u, 1u);
  uint2 k3 = tf2x32(kk.x, kk.y, 0u, 2u);
  const float MA = (float)(20.0 * 3.14159265358979323846 / 180.0);
  float angle  = fmaxf(-MA,   u01f(rb32(k1.x, k1.y, 0u)) * (MA - (-MA)) + (-MA));
  float bright = fmaxf(-0.3f, u01f(rb32(k3.x, k3.y, 0u)) * (0.3f - (-0.3f)) + (-0.3f));

  const float* bx = boxes + (size_t)t * 4;
  float ymin = bx[0], xmin = bx[1], ymax = bx[2], xmax = bx[3];
  float sc = scale_p[0];
  float h = ymax - ymin, ww = xmax - xmin;
  float longer = fmaxf(h, ww);
  float ps = floorf(longer * sc);
  float diag = fminf(sqrtf(2.0f) * ps, (float)W_);
  float oy = ymin + h * 0.5f;
  float ox = xmin + ww * 0.5f;
  float y0 = fmaxf(oy - diag * 0.5f, 0.0f);
  float x0 = fmaxf(ox - diag * 0.5f, 0.0f);
  if (y0 + diag > (float)H_) y0 = (float)H_ - diag;
  if (x0 + diag > (float)W_) x0 = (float)W_ - diag;
  float y0i = floorf(y0), x0i = floorf(x0);
  float phi = fmaxf(floorf(ps), 1.0f);
  float diagi = floorf(diag);
  float validf = ((phi * phi) > 60.0f) ? 1.0f : 0.0f;
  float c = (diagi - 1.0f) * 0.5f;
  float top = floorf((diagi - phi) * 0.5f);

  float* P = params + t * 16;
  P[0] = y0i; P[1] = x0i; P[2] = diagi; P[3] = phi;
  P[4] = c;
  P[5] = (float)cos((double)angle);   // correctly-rounded f32 cos
  P[6] = (float)sin((double)angle);
  P[7] = top;
  P[8] = bright; P[9] = (float)PH_ / phi; P[10] = 0.0f; P[11] = validf;
  P[12] = __uint_as_float(k2.x); P[13] = __uint_as_float(k2.y); P[14] = 0.0f; P[15] = 0.0f;
}

// ---------------- per-tile active-box bitmask ----------------
// One thread per tile; t == blockIdx of copy/paint grids (same decode).
__global__ __launch_bounds__(256) void cull_kernel(const float* __restrict__ params,
                                                   uint32_t* __restrict__ tilemask) {
  int t = blockIdx.x * 256 + threadIdx.x;
  if (t >= NTILES) return;
  int b  = (t & 7) * 2 + ((t >> 3) & 1);
  int tl = t >> 4;
  int ty = tl / TILES_X;
  int tx = tl - ty * TILES_X;
  const float* Pb = params + b * N_ * 16;
  float ys = (float)(ty * TROWS), ye = (float)(ty * TROWS + TROWS - 1);
  float xs = (float)(tx * TCOLS), xe = (float)(tx * TCOLS + TCOLS - 1);
  uint32_t m = 0;
  for (int n = 0; n < N_; n++) {
    const float* P = Pb + n * 16;
    if (P[11] == 0.0f) continue;
    float last = P[2] - 1.0f;               // diagi-1
    if (P[0] + last < ys || P[0] > ye) continue;   // row overlap
    if (P[1] + last < xs || P[1] > xe) continue;   // col overlap
    m |= (1u << n);
  }
  tilemask[t] = m;
}

// ---------------- per-image means (deterministic partials) ----------------
// UNCHANGED summation order & element assignment — dvals bits depend on it.
__global__ __launch_bounds__(256) void reduce_kernel(
    const float* __restrict__ images, const float* __restrict__ patch,
    const float* __restrict__ wb, double* __restrict__ partials) {
  int b = blockIdx.y, j = blockIdx.x, t = threadIdx.x;
  const float* img = images + (size_t)b * IMG_ELEMS;
  double s = 0.0;
  for (int i = j * 256 + t; i < IMG_ELEMS; i += 64 * 256) s += (double)img[i];
  float w0 = wb[b*8+0], w1 = wb[b*8+1], w2 = wb[b*8+2];
  float b0 = wb[b*8+3], b1 = wb[b*8+4], b2 = wb[b*8+5];
  double sp = 0.0;
  for (int i = j * 256 + t; i < PATCH_ELEMS; i += 64 * 256) {
    int q = i / 3; int ch = i - q * 3;
    float wv = (ch == 0) ? w0 : ((ch == 1) ? w1 : w2);
    float bv = (ch == 0) ? b0 : ((ch == 1) ? b1 : b2);
    float pv = fminf(fmaxf(wv * patch[i] + bv, -1.0f), 1.0f);
    sp += (double)pv;
  }
  __shared__ double sh[256];
  sh[t] = s; __syncthreads();
  for (int o = 128; o > 0; o >>= 1) { if (t < o) sh[t] += sh[t + o]; __syncthreads(); }
  if (t == 0) partials[((size_t)b * 64 + j) * 2 + 0] = sh[0];
  __syncthreads();
  sh[t] = sp; __syncthreads();
  for (int o = 128; o > 0; o >>= 1) { if (t < o) sh[t] += sh[t + o]; __syncthreads(); }
  if (t == 0) partials[((size_t)b * 64 + j) * 2 + 1] = sh[0];
}

// ---------------- dvals: same serial-64 order as all prior rounds ----------------
__global__ void finalize_kernel(const double* __restrict__ partials, float* __restrict__ dvals) {
  int t = threadIdx.x;
  if (t < B_) {
    double si = 0.0, sp = 0.0;
    for (int j = 0; j < 64; j++) {
      si += partials[((size_t)t * 64 + j) * 2 + 0];
      sp += partials[((size_t)t * 64 + j) * 2 + 1];
    }
    float mi = (float)(si / (double)IMG_ELEMS);
    float mp = (float)(sp / (double)PATCH_ELEMS);
    dvals[t] = mi - mp;
  }
}

// ---------------- per-image adjusted patch (reference order: clip(clip(w*p+b)+dsh)) ----------------
__global__ __launch_bounds__(256) void patch_adjust_kernel(
    const float* __restrict__ patch, const float* __restrict__ wb,
    const float* __restrict__ dvals, float* __restrict__ padj) {
  int b = blockIdx.y;
  float w0 = wb[b*8+0], w1 = wb[b*8+1], w2 = wb[b*8+2];
  float b0 = wb[b*8+3], b1 = wb[b*8+4], b2 = wb[b*8+5];
  float dsh = dvals[b];
  float* dst = padj + (size_t)b * PATCH_ELEMS;
  int i0 = (blockIdx.x * 256 + threadIdx.x) * 4;
  if (i0 + 4 <= PATCH_ELEMS) {
    f32x4 pv = *(const f32x4*)(patch + i0);
    float o[4];
#pragma unroll
    for (int e = 0; e < 4; e++) {
      int ch = (i0 + e) % 3;
      float wv = (ch == 0) ? w0 : ((ch == 1) ? w1 : w2);
      float bv = (ch == 0) ? b0 : ((ch == 1) ? b1 : b2);
      float a = fminf(fmaxf(wv * pv[e] + bv, -1.0f), 1.0f);
      o[e] = fminf(fmaxf(a + dsh, -1.0f), 1.0f);
    }
    f32x4 ov = {o[0], o[1], o[2], o[3]};
    *(f32x4*)(dst + i0) = ov;
  }
}

// ---------------- copy kernel: untouched tiles only (pure streaming) ----------------
__global__ __launch_bounds__(256) void copy_kernel(
    const float* __restrict__ images, const uint32_t* __restrict__ tilemask,
    float* __restrict__ out) {
  int bid = blockIdx.x;
  if (tilemask[bid] != 0u) return;            // painted: handled by paint_kernel
  int b  = (bid & 7) * 2 + ((bid >> 3) & 1);
  int tl = bid >> 4;
  int ty = tl / TILES_X;
  int tx = tl - ty * TILES_X;
  int tid = threadIdx.x;
  int lane = tid & 63;
  int wv   = tid >> 6;
  size_t ibase = (size_t)b * IMG_ELEMS;
  size_t moff  = (size_t)B_ * IMG_ELEMS;
  const f32x4 z = {0.0f, 0.0f, 0.0f, 0.0f};
#pragma unroll
  for (int k = 0; k < 3; k++) {
    int t4 = k * 64 + lane;                   // 0..191 over wave's 4 rows
    int r  = t4 / 48;
    int c  = t4 - r * 48;
    int row = ty * TROWS + wv * 4 + r;
    size_t fb = ibase + ((size_t)row * W_ + tx * TCOLS) * 3 + (size_t)c * 4;
    f32x4 d = *(const f32x4*)(images + fb);
    __builtin_nontemporal_store(d, (f32x4*)(out + fb));
    __builtin_nontemporal_store(z, (f32x4*)(out + moff + fb));
  }
}

// ---------------- paint kernel: painted tiles only (r7 body, mask-driven) ----------------
template<int PADJ>
__global__ __launch_bounds__(256) void paint_kernel(
    const float* __restrict__ images, const float* __restrict__ patchsrc,
    const float* __restrict__ params, const float* __restrict__ wb,
    const float* __restrict__ dvals, const uint32_t* __restrict__ tilemask,
    float* __restrict__ out) {
  __shared__ float sP[N_ * 16];
  __shared__ float sWB[6];
  __shared__ float sT[TROWS * 192];          // 12 KB transpose buffer

  int bid = blockIdx.x;
  uint32_t mask = tilemask[bid];
  if (mask == 0u) return;                    // untouched: handled by copy_kernel
  int b  = (bid & 7) * 2 + ((bid >> 3) & 1);
  int tl = bid >> 4;
  int ty = tl / TILES_X;
  int tx = tl - ty * TILES_X;
  int tid = threadIdx.x;

  if (tid < N_ * 16) sP[tid] = params[b * N_ * 16 + tid];
  if (PADJ == 0 && tid < 6) sWB[tid] = wb[b * 8 + tid];
  __syncthreads();

  int lane = tid & 63;
  int wv   = tid >> 6;                        // wave 0..3 -> rows 4wv..4wv+3
  size_t ibase = (size_t)b * IMG_ELEMS;
  size_t moff  = (size_t)B_ * IMG_ELEMS;

  const float* patchb = PADJ ? (patchsrc + (size_t)b * PATCH_ELEMS) : patchsrc;
  float dsh = PADJ ? 0.0f : dvals[b];

  // chunk geometry + stage-in: global vectors -> LDS (own wave's rows only)
  int   ck[3], lrk[3];
  size_t fbk[3];
#pragma unroll
  for (int k = 0; k < 3; k++) {
    int t4 = k * 64 + lane;
    int r  = t4 / 48;
    int c  = t4 - r * 48;
    int lr = wv * 4 + r;
    ck[k] = c; lrk[k] = lr;
    fbk[k] = ibase + ((size_t)(ty * TROWS + lr) * W_ + tx * TCOLS) * 3 + (size_t)c * 4;
    f32x4 d = *(const f32x4*)(images + fbk[k]);
    *(f32x4*)(&sT[lr * 192 + c * 4]) = d;
  }

  // per-pixel view: lane = column, j = row within wave's quad
  int   pj[4];  float yfj[4];
  float xf = (float)(tx * TCOLS + lane);
#pragma unroll
  for (int j = 0; j < 4; j++) {
    int row = ty * TROWS + wv * 4 + j;
    pj[j]  = row * W_ + tx * TCOLS + lane;
    yfj[j] = (float)row;
  }

  float orig[12], img[12], mkv[12];
#pragma unroll
  for (int j = 0; j < 4; j++) {
    int base = (wv * 4 + j) * 192 + lane * 3;
    orig[j*3+0] = sT[base + 0];
    orig[j*3+1] = sT[base + 1];
    orig[j*3+2] = sT[base + 2];
  }
#pragma unroll
  for (int e = 0; e < 12; e++) { img[e] = orig[e]; mkv[e] = 0.0f; }

  uint32_t m = mask;
  while (m) {
    int n = __builtin_ctz(m);                 // ascending n: preserves overwrite order
    m &= m - 1u;
    const float* P = sP + n * 16;
    float P0 = P[0], P1 = P[1], diagi = P[2];
    float phi = P[3], c = P[4], ca = P[5], sa = P[6], top = P[7], bright = P[8], sph = P[9];
    uint32_t k2a = __float_as_uint(P[12]);
    uint32_t k2b = __float_as_uint(P[13]);
    float v = xf - P1;
    bool vok = (v >= 0.0f && v < diagi);        // per-lane col test (row-invariant)
    float t2 = v - c;
#pragma unroll
    for (int j = 0; j < 4; j++) {
      float u = yfj[j] - P0;
      if (!(u >= 0.0f && u < diagi)) continue;  // wave-uniform row test
      if (!vok) continue;
      float t1 = u - c;
      float su = (c + ca * t1) - sa * t2;       // same association as before
      float sv = (c + sa * t1) + ca * t2;
      float py = su - top;
      float px = sv - top;
      bool vsrc = (py >= 0.0f) && (py <= phi - 1.0f) && (px >= 0.0f) && (px <= phi - 1.0f);
      if (vsrc) {
        float sy = (py + 0.5f) * sph - 0.5f;
        float sx = (px + 0.5f) * sph - 0.5f;
        float fy = floorf(sy), fx = floorf(sx);
        float wy = sy - fy, wxv = sx - fx;
        int iy0 = min(max((int)fy, 0), PH_ - 1);
        int iy1 = min(iy0 + 1, PH_ - 1);
        int ix0 = min(max((int)fx, 0), PW_ - 1);
        int ix1 = min(ix0 + 1, PW_ - 1);
        int o00 = (iy0 * PW_ + ix0) * 3;
        int o01 = (iy0 * PW_ + ix1) * 3;
        int o10 = (iy1 * PW_ + ix0) * 3;
        int o11 = (iy1 * PW_ + ix1) * 3;
        float omwy = 1.0f - wy, omwx = 1.0f - wxv;
        int nbase = pj[j] * 3;
#pragma unroll
        for (int ch = 0; ch < 3; ch++) {
          float a00, a01, a10, a11;
          if (PADJ) {
            a00 = patchb[o00 + ch];
            a01 = patchb[o01 + ch];
            a10 = patchb[o10 + ch];
            a11 = patchb[o11 + ch];
          } else {
            float wv2 = sWB[ch], bv = sWB[3 + ch];
            a00 = fminf(fmaxf(wv2 * patchb[o00 + ch] + bv, -1.0f), 1.0f);
            a01 = fminf(fmaxf(wv2 * patchb[o01 + ch] + bv, -1.0f), 1.0f);
            a10 = fminf(fmaxf(wv2 * patchb[o10 + ch] + bv, -1.0f), 1.0f);
            a11 = fminf(fmaxf(wv2 * patchb[o11 + ch] + bv, -1.0f), 1.0f);
            a00 = fminf(fmaxf(a00 + dsh, -1.0f), 1.0f);
            a01 = fminf(fmaxf(a01 + dsh, -1.0f), 1.0f);
            a10 = fminf(fmaxf(a10 + dsh, -1.0f), 1.0f);
            a11 = fminf(fmaxf(a11 + dsh, -1.0f), 1.0f);
          }
          float samp = ((a00 * omwy) * omwx) + ((a01 * omwy) * wxv)
                     + ((a10 * wy) * omwx) + ((a11 * wy) * wxv);
          uint32_t bits = rb32(k2a, k2b, (uint32_t)(nbase + ch));
          float nz = fmaxf(-0.1f, u01f(bits) * (0.1f - (-0.1f)) + (-0.1f));
          float imv = fminf(fmaxf((samp + nz) + bright, -1.0f), 1.0f);
          img[j * 3 + ch] = imv;
          mkv[j * 3 + ch] = orig[j * 3 + ch] - imv;
        }
      } else {
        // in square but outside rotated patch: image unchanged, mask = oimg - current bg
#pragma unroll
        for (int ch = 0; ch < 3; ch++) mkv[j * 3 + ch] = orig[j * 3 + ch] - img[j * 3 + ch];
      }
    }
  }

  // img: triplets -> LDS -> vectors -> NT store  (same-wave, in-order DS)
#pragma unroll
  for (int j = 0; j < 4; j++) {
    int base = (wv * 4 + j) * 192 + lane * 3;
    sT[base + 0] = img[j*3+0];
    sT[base + 1] = img[j*3+1];
    sT[base + 2] = img[j*3+2];
  }
#pragma unroll
  for (int k = 0; k < 3; k++) {
    f32x4 d = *(const f32x4*)(&sT[lrk[k] * 192 + ck[k] * 4]);
    __builtin_nontemporal_store(d, (f32x4*)(out + fbk[k]));
  }
#pragma unroll
  for (int j = 0; j < 4; j++) {
    int base = (wv * 4 + j) * 192 + lane * 3;
    sT[base + 0] = mkv[j*3+0];
    sT[base + 1] = mkv[j*3+1];
    sT[base + 2] = mkv[j*3+2];
  }
#pragma unroll
  for (int k = 0; k < 3; k++) {
    f32x4 d = *(const f32x4*)(&sT[lrk[k] * 192 + ck[k] * 4]);
    __builtin_nontemporal_store(d, (f32x4*)(out + moff + fbk[k]));
  }
}

extern "C" void kernel_launch(void* const* d_in, const int* in_sizes, int n_in,
                              void* d_out, int out_size, void* d_ws, size_t ws_size,
                              hipStream_t stream) {
  const float* boxes  = (const float*)d_in[0];
  const float* images = (const float*)d_in[1];
  const float* patch  = (const float*)d_in[2];
  const float* scale  = (const float*)d_in[3];
  float* out = (float*)d_out;

  // ws layout:
  //   [0,16384)        box params (256*16 f32)
  //   [16384,16896)    per-image w/b (16*8 f32)
  //   [16896,16960)    dvals (16 f32)
  //   [17408,43008)    tilemask (6400 u32)
  //   [43008,59392)    partial sums (16*64*2 f64)
  //   [59392,+17.28MB) adjusted patches
  float* params = (float*)d_ws;
  float* wb     = params + B_ * N_ * 16;
  float* dvals  = wb + B_ * 8;
  uint32_t* tilemask = (uint32_t*)((char*)d_ws + 17408);
  double* partials   = (double*)((char*)d_ws + 43008);
  float* padj        = (float*)((char*)d_ws + 59392);
  const size_t PADJ_NEED = 59392 + (size_t)B_ * PATCH_ELEMS * 4;

  setup_kernel<<<1, 256, 0, stream>>>(boxes, scale, params, wb);
  cull_kernel<<<(NTILES + 255) / 256, 256, 0, stream>>>(params, tilemask);
  reduce_kernel<<<dim3(64, B_), 256, 0, stream>>>(images, patch, wb, partials);
  finalize_kernel<<<1, 64, 0, stream>>>(partials, dvals);
  copy_kernel<<<NTILES, 256, 0, stream>>>(images, tilemask, out);
  if (ws_size >= PADJ_NEED) {
    patch_adjust_kernel<<<dim3((PATCH_ELEMS + 1023) / 1024, B_), 256, 0, stream>>>(
        patch, wb, dvals, padj);
    paint_kernel<1><<<NTILES, 256, 0, stream>>>(
        images, padj, params, wb, dvals, tilemask, out);
  } else {
    paint_kernel<0><<<NTILES, 256, 0, stream>>>(
        images, patch, params, wb, dvals, tilemask, out);
  }
}

// Round 9
// 290.787 us; speedup vs baseline: 1.0629x; 1.0629x over previous
//
#include <hip/hip_runtime.h>
#include <stdint.h>
#include <math.h>

#define B_ 16
#define N_ 16
#define H_ 640
#define W_ 640
#define PH_ 300
#define PW_ 300

#define IMG_ELEMS (H_*W_*3)        // 1228800
#define PATCH_ELEMS (PH_*PW_*3)    // 270000

// tiles: 16 rows x 64 cols; 40 x 10 = 400 tiles/image; 6400 total
#define TROWS 16
#define TCOLS 64
#define TILES_Y (H_/TROWS)
#define TILES_X (W_/TCOLS)
#define TILES_PER_IMG (TILES_Y*TILES_X)
#define NTILES (B_*TILES_PER_IMG)

typedef float f32x4 __attribute__((ext_vector_type(4)));

// ---------------- JAX Threefry-2x32-20, bit-exact ----------------
__device__ __forceinline__ uint2 tf2x32(uint32_t k0, uint32_t k1, uint32_t x0, uint32_t x1) {
  uint32_t k2 = k0 ^ k1 ^ 0x1BD11BDAu;
#define TFR(r) x0 += x1; x1 = (x1 << (r)) | (x1 >> (32 - (r))); x1 ^= x0;
  x0 += k0; x1 += k1;
  TFR(13) TFR(15) TFR(26) TFR(6)
  x0 += k1; x1 += k2 + 1u;
  TFR(17) TFR(29) TFR(16) TFR(24)
  x0 += k2; x1 += k0 + 2u;
  TFR(13) TFR(15) TFR(26) TFR(6)
  x0 += k0; x1 += k1 + 3u;
  TFR(17) TFR(29) TFR(16) TFR(24)
  x0 += k1; x1 += k2 + 4u;
  TFR(13) TFR(15) TFR(26) TFR(6)
  x0 += k2; x1 += k0 + 5u;
#undef TFR
  return make_uint2(x0, x1);
}

__device__ __forceinline__ uint32_t rb32(uint32_t k0, uint32_t k1, uint32_t i) {
  uint2 o = tf2x32(k0, k1, 0u, i);
  return o.x ^ o.y;
}

__device__ __forceinline__ float u01f(uint32_t bits) {
  return __uint_as_float((bits >> 9) | 0x3F800000u) - 1.0f;
}

// XLA f32 ErfInv (Giles polynomial) — matches lax.erf_inv
__device__ __forceinline__ float erfinv32(float x) {
  float w = -log1pf(-x * x);
  float p;
  if (w < 5.0f) {
    w = w - 2.5f;
    p = 2.81022636e-08f;
    p = fmaf(p, w, 3.43273939e-07f);
    p = fmaf(p, w, -3.5233877e-06f);
    p = fmaf(p, w, -4.39150654e-06f);
    p = fmaf(p, w, 0.00021858087f);
    p = fmaf(p, w, -0.00125372503f);
    p = fmaf(p, w, -0.00417768164f);
    p = fmaf(p, w, 0.246640727f);
    p = fmaf(p, w, 1.50140941f);
  } else {
    w = sqrtf(w) - 3.0f;
    p = -0.000200214257f;
    p = fmaf(p, w, 0.000100950558f);
    p = fmaf(p, w, 0.00134934322f);
    p = fmaf(p, w, -0.00367342844f);
    p = fmaf(p, w, 0.00573950773f);
    p = fmaf(p, w, -0.0076224613f);
    p = fmaf(p, w, 0.00943887047f);
    p = fmaf(p, w, 1.00167406f);
    p = fmaf(p, w, 2.83297682f);
  }
  return p * x;
}

__device__ __forceinline__ float jnormal(uint32_t bits) {
  float lo = __uint_as_float(0xBF7FFFFFu);  // nextafterf(-1,0)
  float span = 1.0f - lo;                   // rounds to 2.0f, same as XLA
  float u = fmaxf(lo, u01f(bits) * span + lo);
  return 1.4142135623730951f * erfinv32(u);
}

// ---------------- per-image means (deterministic partials) ----------------
// Self-sufficient: recomputes the 6 w/b values in-block (same expressions ->
// same bits as setup). Summation order & element assignment UNCHANGED —
// dvals bits depend on it.
__global__ __launch_bounds__(256) void reduce_kernel(
    const float* __restrict__ images, const float* __restrict__ patch,
    double* __restrict__ partials) {
  int b = blockIdx.y, j = blockIdx.x, t = threadIdx.x;
  __shared__ float swb[6];
  if (t < 6) {
    uint2 kb  = tf2x32(0u, 42u, 0u, (uint32_t)b);
    uint2 kw  = tf2x32(kb.x, kb.y, 0u, 0u);
    uint2 kbk = tf2x32(kb.x, kb.y, 0u, 1u);
    swb[t] = (t < 3) ? (jnormal(rb32(kw.x,  kw.y,  (uint32_t)t)) * 0.1f + 0.5f)
                     : (jnormal(rb32(kbk.x, kbk.y, (uint32_t)(t - 3))) * 0.01f);
  }
  __syncthreads();
  const float* img = images + (size_t)b * IMG_ELEMS;
  double s = 0.0;
  for (int i = j * 256 + t; i < IMG_ELEMS; i += 64 * 256) s += (double)img[i];
  float w0 = swb[0], w1 = swb[1], w2 = swb[2];
  float b0 = swb[3], b1 = swb[4], b2 = swb[5];
  double sp = 0.0;
  for (int i = j * 256 + t; i < PATCH_ELEMS; i += 64 * 256) {
    int q = i / 3; int ch = i - q * 3;
    float wv = (ch == 0) ? w0 : ((ch == 1) ? w1 : w2);
    float bv = (ch == 0) ? b0 : ((ch == 1) ? b1 : b2);
    float pv = fminf(fmaxf(wv * patch[i] + bv, -1.0f), 1.0f);
    sp += (double)pv;
  }
  __shared__ double sh[256];
  sh[t] = s; __syncthreads();
  for (int o = 128; o > 0; o >>= 1) { if (t < o) sh[t] += sh[t + o]; __syncthreads(); }
  if (t == 0) partials[((size_t)b * 64 + j) * 2 + 0] = sh[0];
  __syncthreads();
  sh[t] = sp; __syncthreads();
  for (int o = 128; o > 0; o >>= 1) { if (t < o) sh[t] += sh[t + o]; __syncthreads(); }
  if (t == 0) partials[((size_t)b * 64 + j) * 2 + 1] = sh[0];
}

// ---------------- setup + finalize fused (1 block, 256 threads) ----------------
// params[t*16]: 0 y0i, 1 x0i, 2 diagi, 3 phi, 4 c, 5 ca, 6 sa, 7 top,
//               8 bright, 9 300/phi, 10 unused, 11 valid, 12 k2a, 13 k2b
// dvals: same serial-64 summation order as all prior rounds.
__global__ void setup_finalize_kernel(
    const float* __restrict__ boxes, const float* __restrict__ scale_p,
    const double* __restrict__ partials,
    float* __restrict__ params, float* __restrict__ wb, float* __restrict__ dvals) {
  int t = threadIdx.x;
  if (t < B_) {
    double si = 0.0, sp = 0.0;
    for (int j = 0; j < 64; j++) {
      si += partials[((size_t)t * 64 + j) * 2 + 0];
      sp += partials[((size_t)t * 64 + j) * 2 + 1];
    }
    float mi = (float)(si / (double)IMG_ELEMS);
    float mp = (float)(sp / (double)PATCH_ELEMS);
    dvals[t] = mi - mp;
  }
  if (t >= B_*N_) return;
  int b = t >> 4, n = t & 15;
  uint2 kb = tf2x32(0u, 42u, 0u, (uint32_t)b);
  uint2 kw  = tf2x32(kb.x, kb.y, 0u, 0u);
  uint2 kbk = tf2x32(kb.x, kb.y, 0u, 1u);
  uint2 kl  = tf2x32(kb.x, kb.y, 0u, 2u);
  if (n == 0) {
    wb[b*8+0] = jnormal(rb32(kw.x,  kw.y,  0u)) * 0.1f + 0.5f;
    wb[b*8+1] = jnormal(rb32(kw.x,  kw.y,  1u)) * 0.1f + 0.5f;
    wb[b*8+2] = jnormal(rb32(kw.x,  kw.y,  2u)) * 0.1f + 0.5f;
    wb[b*8+3] = jnormal(rb32(kbk.x, kbk.y, 0u)) * 0.01f;
    wb[b*8+4] = jnormal(rb32(kbk.x, kbk.y, 1u)) * 0.01f;
    wb[b*8+5] = jnormal(rb32(kbk.x, kbk.y, 2u)) * 0.01f;
  }
  uint2 kk = tf2x32(kl.x, kl.y, 0u, (uint32_t)n);
  uint2 k1 = tf2x32(kk.x, kk.y, 0u, 0u);
  uint2 k2 = tf2x32(kk.x, kk.y, 0u, 1u);
  uint2 k3 = tf2x32(kk.x, kk.y, 0u, 2u);
  const float MA = (float)(20.0 * 3.14159265358979323846 / 180.0);
  float angle  = fmaxf(-MA,   u01f(rb32(k1.x, k1.y, 0u)) * (MA - (-MA)) + (-MA));
  float bright = fmaxf(-0.3f, u01f(rb32(k3.x, k3.y, 0u)) * (0.3f - (-0.3f)) + (-0.3f));

  const float* bx = boxes + (size_t)t * 4;
  float ymin = bx[0], xmin = bx[1], ymax = bx[2], xmax = bx[3];
  float sc = scale_p[0];
  float h = ymax - ymin, ww = xmax - xmin;
  float longer = fmaxf(h, ww);
  float ps = floorf(longer * sc);
  float diag = fminf(sqrtf(2.0f) * ps, (float)W_);
  float oy = ymin + h * 0.5f;
  float ox = xmin + ww * 0.5f;
  float y0 = fmaxf(oy - diag * 0.5f, 0.0f);
  float x0 = fmaxf(ox - diag * 0.5f, 0.0f);
  if (y0 + diag > (float)H_) y0 = (float)H_ - diag;
  if (x0 + diag > (float)W_) x0 = (float)W_ - diag;
  float y0i = floorf(y0), x0i = floorf(x0);
  float phi = fmaxf(floorf(ps), 1.0f);
  float diagi = floorf(diag);
  float validf = ((phi * phi) > 60.0f) ? 1.0f : 0.0f;
  float c = (diagi - 1.0f) * 0.5f;
  float top = floorf((diagi - phi) * 0.5f);

  float* P = params + t * 16;
  P[0] = y0i; P[1] = x0i; P[2] = diagi; P[3] = phi;
  P[4] = c;
  P[5] = (float)cos((double)angle);   // correctly-rounded f32 cos
  P[6] = (float)sin((double)angle);
  P[7] = top;
  P[8] = bright; P[9] = (float)PH_ / phi; P[10] = 0.0f; P[11] = validf;
  P[12] = __uint_as_float(k2.x); P[13] = __uint_as_float(k2.y); P[14] = 0.0f; P[15] = 0.0f;
}

// ---------------- main compose: 2D tiles (16x64), same-wave LDS transpose ----------------
// r7 body, inline patch adjust (patch is 1.08 MB -> L2-resident on every XCD).
// Tile = 16 rows x 64 cols. Wave wv owns rows 4wv..4wv+3 (lane = column).
// All global I/O is coalesced f32x4 (3 loads + 6 NT stores per thread).
__global__ __launch_bounds__(256) void main_kernel(
    const float* __restrict__ images, const float* __restrict__ patch,
    const float* __restrict__ params, const float* __restrict__ wb,
    const float* __restrict__ dvals, float* __restrict__ out) {
  __shared__ float sP[N_ * 16];
  __shared__ float sWB[6];
  __shared__ int sList[N_];
  __shared__ int sCount;
  __shared__ float sT[TROWS * 192];          // 12 KB transpose buffer

  // bijective decode: consecutive bids round-robin XCDs (image locality)
  int bid = blockIdx.x;
  int b  = (bid & 7) * 2 + ((bid >> 3) & 1);
  int tl = bid >> 4;                          // 0..399 tile within image
  int ty = tl / TILES_X;                      // 0..39
  int tx = tl - ty * TILES_X;                 // 0..9
  int tid = threadIdx.x;

  if (tid < N_ * 16) sP[tid] = params[b * N_ * 16 + tid];
  if (tid < 6) sWB[tid] = wb[b * 8 + tid];
  if (tid == 0) {
    const float* Pb = params + b * N_ * 16;
    float ys = (float)(ty * TROWS), ye = (float)(ty * TROWS + TROWS - 1);
    float xs = (float)(tx * TCOLS), xe = (float)(tx * TCOLS + TCOLS - 1);
    int cnt = 0;
    for (int n = 0; n < N_; n++) {
      const float* P = Pb + n * 16;
      if (P[11] == 0.0f) continue;
      float last = P[2] - 1.0f;               // diagi-1
      if (P[0] + last < ys || P[0] > ye) continue;   // row overlap
      if (P[1] + last < xs || P[1] > xe) continue;   // col overlap
      sList[cnt++] = n;                       // ascending n: preserves overwrite order
    }
    sCount = cnt;
  }
  __syncthreads();

  int lane = tid & 63;
  int wv   = tid >> 6;                        // wave 0..3 -> rows 4wv..4wv+3
  size_t ibase = (size_t)b * IMG_ELEMS;
  size_t moff  = (size_t)B_ * IMG_ELEMS;

  // chunk geometry: thread's 3 coalesced f32x4 chunks within its wave's rows
  int   ck[3], lrk[3];
  size_t fbk[3];
#pragma unroll
  for (int k = 0; k < 3; k++) {
    int t4 = k * 64 + lane;                   // 0..191 over wave's 4 rows
    int r  = t4 / 48;
    int c  = t4 - r * 48;
    int lr = wv * 4 + r;                      // local row in tile
    ck[k] = c; lrk[k] = lr;
    fbk[k] = ibase + ((size_t)(ty * TROWS + lr) * W_ + tx * TCOLS) * 3 + (size_t)c * 4;
  }

  if (sCount == 0) {
    const f32x4 z = {0.0f, 0.0f, 0.0f, 0.0f};
#pragma unroll
    for (int k = 0; k < 3; k++) {
      f32x4 d = *(const f32x4*)(images + fbk[k]);
      __builtin_nontemporal_store(d, (f32x4*)(out + fbk[k]));
      __builtin_nontemporal_store(z, (f32x4*)(out + moff + fbk[k]));
    }
    return;
  }

  // ---- painted path ----
  float dsh = dvals[b];

  // stage-in: global vectors -> LDS (own wave's rows only)
#pragma unroll
  for (int k = 0; k < 3; k++) {
    f32x4 d = *(const f32x4*)(images + fbk[k]);
    *(f32x4*)(&sT[lrk[k] * 192 + ck[k] * 4]) = d;
  }

  // per-pixel view: lane = column, j = row within wave's quad
  int   pj[4];  float yfj[4];
  float xf = (float)(tx * TCOLS + lane);
#pragma unroll
  for (int j = 0; j < 4; j++) {
    int row = ty * TROWS + wv * 4 + j;
    pj[j]  = row * W_ + tx * TCOLS + lane;
    yfj[j] = (float)row;
  }

  float orig[12], img[12], mkv[12];
#pragma unroll
  for (int j = 0; j < 4; j++) {
    int base = (wv * 4 + j) * 192 + lane * 3;
    orig[j*3+0] = sT[base + 0];
    orig[j*3+1] = sT[base + 1];
    orig[j*3+2] = sT[base + 2];
  }
#pragma unroll
  for (int e = 0; e < 12; e++) { img[e] = orig[e]; mkv[e] = 0.0f; }

  int cnt = sCount;
  for (int li = 0; li < cnt; li++) {
    const float* P = sP + sList[li] * 16;
    float P0 = P[0], P1 = P[1], diagi = P[2];
    float phi = P[3], c = P[4], ca = P[5], sa = P[6], top = P[7], bright = P[8], sph = P[9];
    uint32_t k2a = __float_as_uint(P[12]);
    uint32_t k2b = __float_as_uint(P[13]);
    float v = xf - P1;
    bool vok = (v >= 0.0f && v < diagi);        // per-lane col test (row-invariant)
    float t2 = v - c;
#pragma unroll
    for (int j = 0; j < 4; j++) {
      float u = yfj[j] - P0;
      if (!(u >= 0.0f && u < diagi)) continue;  // wave-uniform row test
      if (!vok) continue;
      float t1 = u - c;
      float su = (c + ca * t1) - sa * t2;       // same association as before
      float sv = (c + sa * t1) + ca * t2;
      float py = su - top;
      float px = sv - top;
      bool vsrc = (py >= 0.0f) && (py <= phi - 1.0f) && (px >= 0.0f) && (px <= phi - 1.0f);
      if (vsrc) {
        float sy = (py + 0.5f) * sph - 0.5f;
        float sx = (px + 0.5f) * sph - 0.5f;
        float fy = floorf(sy), fx = floorf(sx);
        float wy = sy - fy, wxv = sx - fx;
        int iy0 = min(max((int)fy, 0), PH_ - 1);
        int iy1 = min(iy0 + 1, PH_ - 1);
        int ix0 = min(max((int)fx, 0), PW_ - 1);
        int ix1 = min(ix0 + 1, PW_ - 1);
        int o00 = (iy0 * PW_ + ix0) * 3;
        int o01 = (iy0 * PW_ + ix1) * 3;
        int o10 = (iy1 * PW_ + ix0) * 3;
        int o11 = (iy1 * PW_ + ix1) * 3;
        float omwy = 1.0f - wy, omwx = 1.0f - wxv;
        int nbase = pj[j] * 3;
#pragma unroll
        for (int ch = 0; ch < 3; ch++) {
          float wv2 = sWB[ch], bv = sWB[3 + ch];
          float a00 = fminf(fmaxf(wv2 * patch[o00 + ch] + bv, -1.0f), 1.0f);
          float a01 = fminf(fmaxf(wv2 * patch[o01 + ch] + bv, -1.0f), 1.0f);
          float a10 = fminf(fmaxf(wv2 * patch[o10 + ch] + bv, -1.0f), 1.0f);
          float a11 = fminf(fmaxf(wv2 * patch[o11 + ch] + bv, -1.0f), 1.0f);
          a00 = fminf(fmaxf(a00 + dsh, -1.0f), 1.0f);
          a01 = fminf(fmaxf(a01 + dsh, -1.0f), 1.0f);
          a10 = fminf(fmaxf(a10 + dsh, -1.0f), 1.0f);
          a11 = fminf(fmaxf(a11 + dsh, -1.0f), 1.0f);
          float samp = ((a00 * omwy) * omwx) + ((a01 * omwy) * wxv)
                     + ((a10 * wy) * omwx) + ((a11 * wy) * wxv);
          uint32_t bits = rb32(k2a, k2b, (uint32_t)(nbase + ch));
          float nz = fmaxf(-0.1f, u01f(bits) * (0.1f - (-0.1f)) + (-0.1f));
          float imv = fminf(fmaxf((samp + nz) + bright, -1.0f), 1.0f);
          img[j * 3 + ch] = imv;
          mkv[j * 3 + ch] = orig[j * 3 + ch] - imv;
        }
      } else {
        // in square but outside rotated patch: image unchanged, mask = oimg - current bg
#pragma unroll
        for (int ch = 0; ch < 3; ch++) mkv[j * 3 + ch] = orig[j * 3 + ch] - img[j * 3 + ch];
      }
    }
  }

  // img: triplets -> LDS -> vectors -> NT store  (same-wave, in-order DS)
#pragma unroll
  for (int j = 0; j < 4; j++) {
    int base = (wv * 4 + j) * 192 + lane * 3;
    sT[base + 0] = img[j*3+0];
    sT[base + 1] = img[j*3+1];
    sT[base + 2] = img[j*3+2];
  }
#pragma unroll
  for (int k = 0; k < 3; k++) {
    f32x4 d = *(const f32x4*)(&sT[lrk[k] * 192 + ck[k] * 4]);
    __builtin_nontemporal_store(d, (f32x4*)(out + fbk[k]));
  }
#pragma unroll
  for (int j = 0; j < 4; j++) {
    int base = (wv * 4 + j) * 192 + lane * 3;
    sT[base + 0] = mkv[j*3+0];
    sT[base + 1] = mkv[j*3+1];
    sT[base + 2] = mkv[j*3+2];
  }
#pragma unroll
  for (int k = 0; k < 3; k++) {
    f32x4 d = *(const f32x4*)(&sT[lrk[k] * 192 + ck[k] * 4]);
    __builtin_nontemporal_store(d, (f32x4*)(out + moff + fbk[k]));
  }
}

extern "C" void kernel_launch(void* const* d_in, const int* in_sizes, int n_in,
                              void* d_out, int out_size, void* d_ws, size_t ws_size,
                              hipStream_t stream) {
  const float* boxes  = (const float*)d_in[0];
  const float* images = (const float*)d_in[1];
  const float* patch  = (const float*)d_in[2];
  const float* scale  = (const float*)d_in[3];
  float* out = (float*)d_out;

  // ws layout: [0,16384) box params; [16384,16896) per-image w/b; [16896,16960) dvals;
  //            [20480,36864) partial sums (16*64*2 f64)
  float* params = (float*)d_ws;
  float* wb     = params + B_ * N_ * 16;
  float* dvals  = wb + B_ * 8;
  double* partials = (double*)((char*)d_ws + 20480);

  reduce_kernel<<<dim3(64, B_), 256, 0, stream>>>(images, patch, partials);
  setup_finalize_kernel<<<1, 256, 0, stream>>>(boxes, scale, partials, params, wb, dvals);
  main_kernel<<<NTILES, 256, 0, stream>>>(images, patch, params, wb, dvals, out);
}